// Round 13
// baseline (87.612 us; speedup 1.0000x reference)
//
#include <hip/hip_runtime.h>
#include <hip/hip_bf16.h>
#include <math.h>

// CapsuleLayer dynamic routing.
// Identity: routing bias after round r = hat · (v0+...+v_{r-1}) — each route
// round only needs veff = running sum of v, 160 floats per b.
// Pipeline (2 kernels, 1 gap; NO cross-block atomics/fences — R9 lesson):
//   k1        : hat = x·W -> bf16 ws + round-1 partials sPart1  (~31 us,
//               at combined HBM-write + L3-read ceiling; R6/R8/R10/R11
//               experiments all neutral — do not touch)
//   route_all : one block per b (grid == 1 block/CU): veff1 -> round 2 ->
//               veff2 -> round 3 -> out. First KEEP=9 batches of hat[b] are
//               RETAINED IN VGPRs across rounds (72 regs/thread) so round 3
//               re-reads only half of hat from L3.

#define B_ 256
#define I_ 1152
#define D_ 8
#define C_ 10
#define O_ 16
#define CO_ (C_*O_)   // 160
#define EPS_ 1e-7f

// k1 geometry (proven): 4 ig x 80 (c,o2) = 320 thr; BT=16.
#define IC1 16
#define NIC1 (I_/IC1)   // 72
#define BT 16
#define NBT (B_/BT)     // 16
#define T1 320
// route_all geometry: 64 il x 10 c = 640 threads; 18 batches of 64 i.
#define TRA 640
#define NBATCH (I_/64)  // 18
#define KEEP 9          // batches cached in VGPRs between rounds

// ---------------------------------------------------------------------------
// K1: hat[b,i,c,o] = sum_d x[b,i,d] W[i,c,d,o]  (bf16), plus round-1 partials.
// ---------------------------------------------------------------------------
__global__ __launch_bounds__(T1) void k1_hat(
    const float* __restrict__ x,       // [B,I,D]
    const float* __restrict__ W,       // [I,C,D,O]
    __hip_bfloat16* __restrict__ hat,  // [B,I,CO]
    float* __restrict__ sPart1)        // [NIC1][B][CO]
{
    __shared__ float xs[BT * IC1 * D_];   // 8 KB
    __shared__ float sred[BT][CO_];       // 10 KB
    const int tid = threadIdx.x;
    const int ic = blockIdx.x, bt = blockIdx.y;
    const int i0 = ic * IC1, b0 = bt * BT;

    // cooperative x tile load, float4 (512; rows are 32B-aligned)
    for (int j = tid; j < BT * IC1 * D_ / 4; j += T1) {
        const int bb = j >> 5, r = j & 31;
        ((float4*)xs)[j] =
            *(const float4*)&x[(((size_t)(b0 + bb)) * I_ + i0) * D_ + r * 4];
    }
    __syncthreads();

    const int ig = tid / 80, r = tid % 80;
    const int c = r / 8, o2 = r % 8;

    float2 acc[BT];
    #pragma unroll
    for (int bb = 0; bb < BT; ++bb) acc[bb] = make_float2(0.0f, 0.0f);

    const float2* W2 = (const float2*)W;

    for (int k = 0; k < IC1 / 4; ++k) {
        const int il = ig * (IC1 / 4) + k;
        const int i = i0 + il;
        float2 wv[D_];
        const float2* wp = W2 + ((size_t)i * C_ + c) * (D_ * O_ / 2) + o2;
        #pragma unroll
        for (int d = 0; d < D_; ++d) wv[d] = wp[d * (O_ / 2)];
        #pragma unroll
        for (int bb = 0; bb < BT; ++bb) {
            const float4* xp4 = (const float4*)&xs[(bb * IC1 + il) * D_];
            const float4 xa = xp4[0];   // ds_read_b128 (broadcast)
            const float4 xb = xp4[1];
            const float xv[D_] = {xa.x, xa.y, xa.z, xa.w, xb.x, xb.y, xb.z, xb.w};
            float h0 = 0.0f, h1 = 0.0f;
            #pragma unroll
            for (int d = 0; d < D_; ++d) {
                h0 = fmaf(xv[d], wv[d].x, h0);
                h1 = fmaf(xv[d], wv[d].y, h1);
            }
            acc[bb].x += h0; acc[bb].y += h1;
            *(__hip_bfloat162*)&hat[((size_t)(b0 + bb) * I_ + i) * CO_ + c * O_ + o2 * 2] =
                __float22bfloat162_rn(make_float2(h0, h1));
        }
    }

    // staged reduce over the 4 ig groups (deterministic)
    if (ig == 0) {
        #pragma unroll
        for (int bb = 0; bb < BT; ++bb) {
            sred[bb][c * O_ + o2 * 2]     = acc[bb].x;
            sred[bb][c * O_ + o2 * 2 + 1] = acc[bb].y;
        }
    }
    __syncthreads();
    #pragma unroll
    for (int g = 1; g < 4; ++g) {
        if (ig == g) {
            #pragma unroll
            for (int bb = 0; bb < BT; ++bb) {
                sred[bb][c * O_ + o2 * 2]     += acc[bb].x;
                sred[bb][c * O_ + o2 * 2 + 1] += acc[bb].y;
            }
        }
        __syncthreads();
    }
    if (tid < CO_) {
        for (int bb = 0; bb < BT; ++bb)
            sPart1[((size_t)ic * B_ + (b0 + bb)) * CO_ + tid] = sred[bb][tid];
    }
}

// ---------------------------------------------------------------------------
// route_all: one block per b; 640 thr = (il 0..63, c 0..9).
// veff1 -> round2 (caching first KEEP batches in regs) -> veff2 -> round3
// (reusing cached batches) -> out. One barrier per batch (pb double-buffered,
// write-to-reuse distance 2). All reductions fixed-order -> deterministic.
// ---------------------------------------------------------------------------
__global__ __launch_bounds__(TRA) void k_route_all(
    const __hip_bfloat16* __restrict__ hat,  // [B,I,CO]
    const float* __restrict__ sPart1,        // [NIC1][B][CO]
    float* __restrict__ out)                 // [B,CO]
{
    __shared__ float pb[2][64][C_];       // 5 KB
    __shared__ float sr[64][CO_ + 4];     // 42 KB (+4 pad: bank spread)
    __shared__ float red4[4][CO_];        // 2.5 KB
    __shared__ float veffs[CO_];
    const int tid = threadIdx.x;
    const int il = tid / C_, c = tid % C_;
    const int b = blockIdx.x;
    const int q = tid / CO_;              // 0..3
    const int co = tid % CO_;

    // ---- veff1 = squash((sum_k sPart1[k][b]) / C), 4-way split ----
    {
        float s = 0.0f;
        #pragma unroll 2
        for (int j = 0; j < NIC1 / 4; ++j)
            s += sPart1[((size_t)(q * (NIC1 / 4) + j) * B_ + b) * CO_ + co];
        red4[q][co] = s;
    }
    __syncthreads();
    if (tid < CO_) {
        float s = ((red4[0][tid] + red4[1][tid]) + (red4[2][tid] + red4[3][tid]))
                  * (1.0f / C_);
        float n2 = s * s;
        n2 += __shfl_xor(n2, 1);
        n2 += __shfl_xor(n2, 2);
        n2 += __shfl_xor(n2, 4);
        n2 += __shfl_xor(n2, 8);
        const float sc = n2 / ((1.0f + n2) * sqrtf(n2 + EPS_));
        veffs[tid] = s * sc;
    }
    __syncthreads();

    const size_t baseB = (size_t)b * I_;
    const size_t rowOff = (size_t)il * CO_ + c * O_;

    uint4 kha[KEEP], khb[KEEP];           // 72 VGPR: hat cache across rounds

    // =================== ROUND 2 ===================
    {
        float vr[O_];
        #pragma unroll
        for (int o = 0; o < O_; ++o) vr[o] = veffs[c * O_ + o];
        float sacc[O_];
        #pragma unroll
        for (int o = 0; o < O_; ++o) sacc[o] = 0.0f;

        uint4 ha, hb2, han, hbn;
        {
            const uint4* p0 = (const uint4*)&hat[baseB * CO_ + rowOff];
            ha = p0[0]; hb2 = p0[1];
        }
        #pragma unroll
        for (int batch = 0; batch < NBATCH; ++batch) {
            if (batch < NBATCH - 1) {   // prefetch next batch's hat row
                const uint4* pn = (const uint4*)
                    &hat[(baseB + (size_t)(batch + 1) * 64) * CO_ + rowOff];
                han = pn[0]; hbn = pn[1];
            }
            if (batch < KEEP) { kha[batch] = ha; khb[batch] = hb2; }
            float hf[O_];
            {
                const unsigned u[8] = {ha.x, ha.y, ha.z, ha.w,
                                       hb2.x, hb2.y, hb2.z, hb2.w};
                #pragma unroll
                for (int t = 0; t < 8; ++t) {
                    hf[2 * t]     = __uint_as_float(u[t] << 16);
                    hf[2 * t + 1] = __uint_as_float(u[t] & 0xffff0000u);
                }
            }
            float p = 0.0f;
            #pragma unroll
            for (int o = 0; o < O_; ++o) p = fmaf(hf[o], vr[o], p);
            pb[batch & 1][il][c] = p;
            __syncthreads();
            float pv[C_];
            #pragma unroll
            for (int qq = 0; qq < C_; ++qq) pv[qq] = pb[batch & 1][il][qq];
            float m = pv[0];
            #pragma unroll
            for (int qq = 1; qq < C_; ++qq) m = fmaxf(m, pv[qq]);
            float sum = 0.0f;
            #pragma unroll
            for (int qq = 0; qq < C_; ++qq) sum += __expf(pv[qq] - m);
            const float route = __expf(p - m) * __builtin_amdgcn_rcpf(sum);
            #pragma unroll
            for (int o = 0; o < O_; ++o) sacc[o] = fmaf(route, hf[o], sacc[o]);
            ha = han; hb2 = hbn;
        }

        #pragma unroll
        for (int o = 0; o < O_; ++o) sr[il][c * O_ + o] = sacc[o];
    }
    __syncthreads();
    {
        float s = 0.0f;
        #pragma unroll
        for (int j = 0; j < 16; ++j) s += sr[q * 16 + j][co];
        red4[q][co] = s;
    }
    __syncthreads();
    if (tid < CO_) {
        float s = (red4[0][tid] + red4[1][tid]) + (red4[2][tid] + red4[3][tid]);
        float n2 = s * s;
        n2 += __shfl_xor(n2, 1);
        n2 += __shfl_xor(n2, 2);
        n2 += __shfl_xor(n2, 4);
        n2 += __shfl_xor(n2, 8);
        const float sc = n2 / ((1.0f + n2) * sqrtf(n2 + EPS_));
        veffs[tid] += s * sc;               // veff2 = veff1 + v1
    }
    __syncthreads();

    // =================== ROUND 3 ===================
    {
        float vr[O_];
        #pragma unroll
        for (int o = 0; o < O_; ++o) vr[o] = veffs[c * O_ + o];
        float sacc[O_];
        #pragma unroll
        for (int o = 0; o < O_; ++o) sacc[o] = 0.0f;

        uint4 ha, hb2, han, hbn;
        ha = kha[0]; hb2 = khb[0];
        #pragma unroll
        for (int batch = 0; batch < NBATCH; ++batch) {
            if (batch + 1 < KEEP) {          // next comes from the reg cache
                han = kha[batch + 1]; hbn = khb[batch + 1];
            } else if (batch < NBATCH - 1) { // next streams from L3
                const uint4* pn = (const uint4*)
                    &hat[(baseB + (size_t)(batch + 1) * 64) * CO_ + rowOff];
                han = pn[0]; hbn = pn[1];
            }
            float hf[O_];
            {
                const unsigned u[8] = {ha.x, ha.y, ha.z, ha.w,
                                       hb2.x, hb2.y, hb2.z, hb2.w};
                #pragma unroll
                for (int t = 0; t < 8; ++t) {
                    hf[2 * t]     = __uint_as_float(u[t] << 16);
                    hf[2 * t + 1] = __uint_as_float(u[t] & 0xffff0000u);
                }
            }
            float p = 0.0f;
            #pragma unroll
            for (int o = 0; o < O_; ++o) p = fmaf(hf[o], vr[o], p);
            pb[batch & 1][il][c] = p;
            __syncthreads();
            float pv[C_];
            #pragma unroll
            for (int qq = 0; qq < C_; ++qq) pv[qq] = pb[batch & 1][il][qq];
            float m = pv[0];
            #pragma unroll
            for (int qq = 1; qq < C_; ++qq) m = fmaxf(m, pv[qq]);
            float sum = 0.0f;
            #pragma unroll
            for (int qq = 0; qq < C_; ++qq) sum += __expf(pv[qq] - m);
            const float route = __expf(p - m) * __builtin_amdgcn_rcpf(sum);
            #pragma unroll
            for (int o = 0; o < O_; ++o) sacc[o] = fmaf(route, hf[o], sacc[o]);
            ha = han; hb2 = hbn;
        }

        #pragma unroll
        for (int o = 0; o < O_; ++o) sr[il][c * O_ + o] = sacc[o];
    }
    __syncthreads();
    {
        float s = 0.0f;
        #pragma unroll
        for (int j = 0; j < 16; ++j) s += sr[q * 16 + j][co];
        red4[q][co] = s;
    }
    __syncthreads();
    if (tid < CO_) {
        float s = (red4[0][tid] + red4[1][tid]) + (red4[2][tid] + red4[3][tid]);
        float n2 = s * s;
        n2 += __shfl_xor(n2, 1);
        n2 += __shfl_xor(n2, 2);
        n2 += __shfl_xor(n2, 4);
        n2 += __shfl_xor(n2, 8);
        const float sc = n2 / ((1.0f + n2) * sqrtf(n2 + EPS_));
        out[(size_t)b * CO_ + tid] = s * sc;
    }
}

// ---------------------------------------------------------------------------
// Fallback: fully fused single kernel (~402 us) if ws too small
// ---------------------------------------------------------------------------
#define THREADS 640
#define ILG 8
#define SUBI 4
#define CHUNK (ILG*SUBI)
#define NITER (I_/CHUNK)

__global__ __launch_bounds__(THREADS) void capsule_routing_kernel(
    const float* __restrict__ x, const float* __restrict__ W,
    float* __restrict__ out)
{
    __shared__ float bias[I_ * C_];
    __shared__ float spart[ILG][C_ * O_];
    __shared__ float sv[C_ * O_];
    __shared__ float vv[C_ * O_];
    __shared__ float ech[CHUNK][C_];
    __shared__ float scale[C_];

    const int b   = blockIdx.x;
    const int tid = threadIdx.x;
    for (int j = tid; j < I_ * C_; j += THREADS) bias[j] = 0.0f;
    const int il = tid / 80;
    const int rr = tid % 80;
    const int c  = rr / 8;
    const int o2 = rr % 8;
    const int o0 = o2 * 2;
    const float* xb = x + (size_t)b * I_ * D_;
    const float2* W2 = (const float2*)W;
    __syncthreads();
    {
        float acc0 = 0.0f, acc1 = 0.0f;
        for (int it = 0; it < NITER; ++it) {
            #pragma unroll
            for (int sub = 0; sub < SUBI; ++sub) {
                const int i = it * CHUNK + sub * ILG + il;
                const float* xi = xb + i * D_;
                const float2* wp = W2 + (i * C_ + c) * (D_ * O_ / 2) + o2;
                float h0 = 0.0f, h1 = 0.0f;
                #pragma unroll
                for (int d = 0; d < D_; ++d) {
                    float2 w = wp[d * (O_ / 2)];
                    float xv = xi[d];
                    h0 = fmaf(xv, w.x, h0);
                    h1 = fmaf(xv, w.y, h1);
                }
                acc0 += h0; acc1 += h1;
            }
        }
        spart[il][c * O_ + o0]     = acc0;
        spart[il][c * O_ + o0 + 1] = acc1;
    }
    __syncthreads();
    if (tid < C_ * O_) {
        float s = 0.0f;
        #pragma unroll
        for (int k = 0; k < ILG; ++k) s += spart[k][tid];
        sv[tid] = s * (1.0f / C_);
    }
    __syncthreads();
    if (tid < C_) {
        float n2 = 0.0f;
        #pragma unroll
        for (int o = 0; o < O_; ++o) { float t = sv[tid * O_ + o]; n2 = fmaf(t, t, n2); }
        scale[tid] = n2 / ((1.0f + n2) * sqrtf(n2 + EPS_));
    }
    __syncthreads();
    if (tid < C_ * O_) vv[tid] = sv[tid] * scale[tid / O_];
    __syncthreads();
    for (int pass = 1; pass < 3; ++pass) {
        float sa0 = 0.0f, sa1 = 0.0f;
        for (int it = 0; it < NITER; ++it) {
            float h0s[SUBI], h1s[SUBI];
            const float v0 = vv[c * O_ + o0];
            const float v1 = vv[c * O_ + o0 + 1];
            #pragma unroll
            for (int sub = 0; sub < SUBI; ++sub) {
                const int i = it * CHUNK + sub * ILG + il;
                const float* xi = xb + i * D_;
                const float2* wp = W2 + (i * C_ + c) * (D_ * O_ / 2) + o2;
                float h0 = 0.0f, h1 = 0.0f;
                #pragma unroll
                for (int d = 0; d < D_; ++d) {
                    float2 w = wp[d * (O_ / 2)];
                    float xv = xi[d];
                    h0 = fmaf(xv, w.x, h0);
                    h1 = fmaf(xv, w.y, h1);
                }
                h0s[sub] = h0; h1s[sub] = h1;
                float p = h0 * v0 + h1 * v1;
                p += __shfl_xor(p, 1);
                p += __shfl_xor(p, 2);
                p += __shfl_xor(p, 4);
                if (o2 == 0) bias[i * C_ + c] += p;
            }
            __syncthreads();
            if (tid < CHUNK * C_) {
                const int il2 = tid / C_, cc = tid % C_;
                const int i = it * CHUNK + il2;
                float m = -1e30f;
                #pragma unroll
                for (int k = 0; k < C_; ++k) m = fmaxf(m, bias[i * C_ + k]);
                ech[il2][cc] = __expf(bias[i * C_ + cc] - m);
            }
            __syncthreads();
            #pragma unroll
            for (int sub = 0; sub < SUBI; ++sub) {
                const int icx = sub * ILG + il;
                float sum = 0.0f;
                #pragma unroll
                for (int k = 0; k < C_; ++k) sum += ech[icx][k];
                const float route = ech[icx][c] / sum;
                sa0 = fmaf(route, h0s[sub], sa0);
                sa1 = fmaf(route, h1s[sub], sa1);
            }
            __syncthreads();
        }
        spart[il][c * O_ + o0]     = sa0;
        spart[il][c * O_ + o0 + 1] = sa1;
        __syncthreads();
        if (tid < C_ * O_) {
            float s = 0.0f;
            #pragma unroll
            for (int k = 0; k < ILG; ++k) s += spart[k][tid];
            sv[tid] = s;
        }
        __syncthreads();
        if (tid < C_) {
            float n2 = 0.0f;
            #pragma unroll
            for (int o = 0; o < O_; ++o) { float t = sv[tid * O_ + o]; n2 = fmaf(t, t, n2); }
            scale[tid] = n2 / ((1.0f + n2) * sqrtf(n2 + EPS_));
        }
        __syncthreads();
        if (tid < C_ * O_) vv[tid] = sv[tid] * scale[tid / O_];
        __syncthreads();
    }
    if (tid < C_ * O_) out[(size_t)b * C_ * O_ + tid] = vv[tid];
}

// ---------------------------------------------------------------------------
extern "C" void kernel_launch(void* const* d_in, const int* in_sizes, int n_in,
                              void* d_out, int out_size, void* d_ws, size_t ws_size,
                              hipStream_t stream) {
    (void)in_sizes; (void)n_in; (void)out_size;
    const float* x = (const float*)d_in[0];
    const float* W = (const float*)d_in[1];
    float* out = (float*)d_out;

    const size_t hat_b  = (size_t)B_ * I_ * CO_ * sizeof(__hip_bfloat16); // 94.4 MB
    const size_t sp1_b  = (size_t)NIC1 * B_ * CO_ * sizeof(float);        // 11.8 MB
    const size_t need   = hat_b + sp1_b;                                  // ~106 MB

    if (ws_size >= need) {
        char* p = (char*)d_ws;
        __hip_bfloat16* hat = (__hip_bfloat16*)p;  p += hat_b;
        float* sPart1 = (float*)p;

        k1_hat<<<dim3(NIC1, NBT), T1, 0, stream>>>(x, W, hat, sPart1);
        k_route_all<<<B_, TRA, 0, stream>>>(hat, sPart1, out);
    } else {
        capsule_routing_kernel<<<B_, THREADS, 0, stream>>>(x, W, out);
    }
}

// Round 14
// 61.823 us; speedup vs baseline: 1.4171x; 1.4171x over previous
//
#include <hip/hip_runtime.h>
#include <hip/hip_bf16.h>
#include <math.h>

// CapsuleLayer dynamic routing.
// Identity: routing bias after round r = hat · (v0+...+v_{r-1}) — each route
// round only needs veff = running sum of v, 160 floats per b.
// Pipeline (2 kernels, 1 gap; NO cross-block atomics/fences — R9 lesson):
//   k1        : hat = x·W -> bf16 ws + round-1 partials sPart1  (~31 us,
//               at combined HBM-write + L3-read ceiling; R6/R8/R10/R11
//               experiments all neutral — do not touch)
//   route_all : one block per b (grid == 1 block/CU): veff1 -> round 2 ->
//               veff2 -> round 3 -> out  (~27 us, ~7.4 TB/s effective L3).
// R13 lesson: holding 72 VGPRs of hat across the two rounds gets SPILLED to
// scratch (94 MB of HBM writes, 1.4x slowdown) — do not register-cache hat.

#define B_ 256
#define I_ 1152
#define D_ 8
#define C_ 10
#define O_ 16
#define CO_ (C_*O_)   // 160
#define EPS_ 1e-7f

// k1 geometry (proven): 4 ig x 80 (c,o2) = 320 thr; BT=16.
#define IC1 16
#define NIC1 (I_/IC1)   // 72
#define BT 16
#define NBT (B_/BT)     // 16
#define T1 320
// route_all geometry: 64 il x 10 c = 640 threads; 18 batches of 64 i.
#define TRA 640
#define NBATCH (I_/64)  // 18

// ---------------------------------------------------------------------------
// K1: hat[b,i,c,o] = sum_d x[b,i,d] W[i,c,d,o]  (bf16), plus round-1 partials.
// ---------------------------------------------------------------------------
__global__ __launch_bounds__(T1) void k1_hat(
    const float* __restrict__ x,       // [B,I,D]
    const float* __restrict__ W,       // [I,C,D,O]
    __hip_bfloat16* __restrict__ hat,  // [B,I,CO]
    float* __restrict__ sPart1)        // [NIC1][B][CO]
{
    __shared__ float xs[BT * IC1 * D_];   // 8 KB
    __shared__ float sred[BT][CO_];       // 10 KB
    const int tid = threadIdx.x;
    const int ic = blockIdx.x, bt = blockIdx.y;
    const int i0 = ic * IC1, b0 = bt * BT;

    // cooperative x tile load, float4 (512; rows are 32B-aligned)
    for (int j = tid; j < BT * IC1 * D_ / 4; j += T1) {
        const int bb = j >> 5, r = j & 31;
        ((float4*)xs)[j] =
            *(const float4*)&x[(((size_t)(b0 + bb)) * I_ + i0) * D_ + r * 4];
    }
    __syncthreads();

    const int ig = tid / 80, r = tid % 80;
    const int c = r / 8, o2 = r % 8;

    float2 acc[BT];
    #pragma unroll
    for (int bb = 0; bb < BT; ++bb) acc[bb] = make_float2(0.0f, 0.0f);

    const float2* W2 = (const float2*)W;

    for (int k = 0; k < IC1 / 4; ++k) {
        const int il = ig * (IC1 / 4) + k;
        const int i = i0 + il;
        float2 wv[D_];
        const float2* wp = W2 + ((size_t)i * C_ + c) * (D_ * O_ / 2) + o2;
        #pragma unroll
        for (int d = 0; d < D_; ++d) wv[d] = wp[d * (O_ / 2)];
        #pragma unroll
        for (int bb = 0; bb < BT; ++bb) {
            const float4* xp4 = (const float4*)&xs[(bb * IC1 + il) * D_];
            const float4 xa = xp4[0];   // ds_read_b128 (broadcast)
            const float4 xb = xp4[1];
            const float xv[D_] = {xa.x, xa.y, xa.z, xa.w, xb.x, xb.y, xb.z, xb.w};
            float h0 = 0.0f, h1 = 0.0f;
            #pragma unroll
            for (int d = 0; d < D_; ++d) {
                h0 = fmaf(xv[d], wv[d].x, h0);
                h1 = fmaf(xv[d], wv[d].y, h1);
            }
            acc[bb].x += h0; acc[bb].y += h1;
            *(__hip_bfloat162*)&hat[((size_t)(b0 + bb) * I_ + i) * CO_ + c * O_ + o2 * 2] =
                __float22bfloat162_rn(make_float2(h0, h1));
        }
    }

    // staged reduce over the 4 ig groups (deterministic)
    if (ig == 0) {
        #pragma unroll
        for (int bb = 0; bb < BT; ++bb) {
            sred[bb][c * O_ + o2 * 2]     = acc[bb].x;
            sred[bb][c * O_ + o2 * 2 + 1] = acc[bb].y;
        }
    }
    __syncthreads();
    #pragma unroll
    for (int g = 1; g < 4; ++g) {
        if (ig == g) {
            #pragma unroll
            for (int bb = 0; bb < BT; ++bb) {
                sred[bb][c * O_ + o2 * 2]     += acc[bb].x;
                sred[bb][c * O_ + o2 * 2 + 1] += acc[bb].y;
            }
        }
        __syncthreads();
    }
    if (tid < CO_) {
        for (int bb = 0; bb < BT; ++bb)
            sPart1[((size_t)ic * B_ + (b0 + bb)) * CO_ + tid] = sred[bb][tid];
    }
}

// ---------------------------------------------------------------------------
// route_all: one block per b; 640 thr = (il 0..63, c 0..9).
// veff1 -> round2 -> (reduce+squash) -> veff2 -> round3 -> out.
// One barrier per batch (pb double-buffered); next-batch hat regs prefetched.
// All reductions in fixed order -> deterministic.
// ---------------------------------------------------------------------------
__global__ __launch_bounds__(TRA) void k_route_all(
    const __hip_bfloat16* __restrict__ hat,  // [B,I,CO]
    const float* __restrict__ sPart1,        // [NIC1][B][CO]
    float* __restrict__ out)                 // [B,CO]
{
    __shared__ float pb[2][64][C_];       // 5 KB
    __shared__ float sr[64][CO_ + 4];     // 42 KB (+4 pad: bank spread)
    __shared__ float red4[4][CO_];        // 2.5 KB
    __shared__ float veffs[CO_];
    const int tid = threadIdx.x;
    const int il = tid / C_, c = tid % C_;
    const int b = blockIdx.x;
    const int q = tid / CO_;              // 0..3
    const int co = tid % CO_;

    // ---- veff1 = squash((sum_k sPart1[k][b]) / C), 4-way split ----
    {
        float s = 0.0f;
        #pragma unroll 2
        for (int j = 0; j < NIC1 / 4; ++j)
            s += sPart1[((size_t)(q * (NIC1 / 4) + j) * B_ + b) * CO_ + co];
        red4[q][co] = s;
    }
    __syncthreads();
    if (tid < CO_) {
        float s = ((red4[0][tid] + red4[1][tid]) + (red4[2][tid] + red4[3][tid]))
                  * (1.0f / C_);
        float n2 = s * s;
        n2 += __shfl_xor(n2, 1);
        n2 += __shfl_xor(n2, 2);
        n2 += __shfl_xor(n2, 4);
        n2 += __shfl_xor(n2, 8);
        const float sc = n2 / ((1.0f + n2) * sqrtf(n2 + EPS_));
        veffs[tid] = s * sc;
    }
    __syncthreads();

    const size_t baseB = (size_t)b * I_;

    for (int round = 0; round < 2; ++round) {
        float vr[O_];
        #pragma unroll
        for (int o = 0; o < O_; ++o) vr[o] = veffs[c * O_ + o];
        float sacc[O_];
        #pragma unroll
        for (int o = 0; o < O_; ++o) sacc[o] = 0.0f;

        uint4 ha, hb2, han, hbn;
        {
            const uint4* p0 = (const uint4*)&hat[(baseB + il) * CO_ + c * O_];
            ha = p0[0]; hb2 = p0[1];
        }
        for (int batch = 0; batch < NBATCH; ++batch) {
            if (batch < NBATCH - 1) {   // prefetch next batch's hat row
                const uint4* pn = (const uint4*)
                    &hat[(baseB + (batch + 1) * 64 + il) * CO_ + c * O_];
                han = pn[0]; hbn = pn[1];
            }
            float hf[O_];
            {
                const unsigned u[8] = {ha.x, ha.y, ha.z, ha.w,
                                       hb2.x, hb2.y, hb2.z, hb2.w};
                #pragma unroll
                for (int t = 0; t < 8; ++t) {
                    hf[2 * t]     = __uint_as_float(u[t] << 16);
                    hf[2 * t + 1] = __uint_as_float(u[t] & 0xffff0000u);
                }
            }
            float p = 0.0f;
            #pragma unroll
            for (int o = 0; o < O_; ++o) p = fmaf(hf[o], vr[o], p);
            pb[batch & 1][il][c] = p;
            __syncthreads();
            // local softmax over the 10 logits (same order in all threads)
            float pv[C_];
            #pragma unroll
            for (int qq = 0; qq < C_; ++qq) pv[qq] = pb[batch & 1][il][qq];
            float m = pv[0];
            #pragma unroll
            for (int qq = 1; qq < C_; ++qq) m = fmaxf(m, pv[qq]);
            float sum = 0.0f;
            #pragma unroll
            for (int qq = 0; qq < C_; ++qq) sum += __expf(pv[qq] - m);
            const float route = __expf(p - m) * __builtin_amdgcn_rcpf(sum);
            #pragma unroll
            for (int o = 0; o < O_; ++o) sacc[o] = fmaf(route, hf[o], sacc[o]);
            ha = han; hb2 = hbn;
            // no second barrier: pb is double-buffered; the write to this
            // buffer 2 batches later is ordered by the next batch's barrier.
        }

        // ---- reduce sacc over the 64 il groups (fixed order) ----
        #pragma unroll
        for (int o = 0; o < O_; ++o) sr[il][c * O_ + o] = sacc[o];
        __syncthreads();
        {
            float s = 0.0f;
            #pragma unroll
            for (int j = 0; j < 16; ++j) s += sr[q * 16 + j][co];
            red4[q][co] = s;
        }
        __syncthreads();
        if (tid < CO_) {
            float s = (red4[0][tid] + red4[1][tid]) + (red4[2][tid] + red4[3][tid]);
            float n2 = s * s;
            n2 += __shfl_xor(n2, 1);
            n2 += __shfl_xor(n2, 2);
            n2 += __shfl_xor(n2, 4);
            n2 += __shfl_xor(n2, 8);
            const float sc = n2 / ((1.0f + n2) * sqrtf(n2 + EPS_));
            const float v = s * sc;
            if (round == 0) veffs[tid] += v;           // veff2 = veff1 + v1
            else out[(size_t)b * CO_ + tid] = v;       // final output
        }
        __syncthreads();
    }
}

// ---------------------------------------------------------------------------
// Fallback: fully fused single kernel (~402 us) if ws too small
// ---------------------------------------------------------------------------
#define THREADS 640
#define ILG 8
#define SUBI 4
#define CHUNK (ILG*SUBI)
#define NITER (I_/CHUNK)

__global__ __launch_bounds__(THREADS) void capsule_routing_kernel(
    const float* __restrict__ x, const float* __restrict__ W,
    float* __restrict__ out)
{
    __shared__ float bias[I_ * C_];
    __shared__ float spart[ILG][C_ * O_];
    __shared__ float sv[C_ * O_];
    __shared__ float vv[C_ * O_];
    __shared__ float ech[CHUNK][C_];
    __shared__ float scale[C_];

    const int b   = blockIdx.x;
    const int tid = threadIdx.x;
    for (int j = tid; j < I_ * C_; j += THREADS) bias[j] = 0.0f;
    const int il = tid / 80;
    const int rr = tid % 80;
    const int c  = rr / 8;
    const int o2 = rr % 8;
    const int o0 = o2 * 2;
    const float* xb = x + (size_t)b * I_ * D_;
    const float2* W2 = (const float2*)W;
    __syncthreads();
    {
        float acc0 = 0.0f, acc1 = 0.0f;
        for (int it = 0; it < NITER; ++it) {
            #pragma unroll
            for (int sub = 0; sub < SUBI; ++sub) {
                const int i = it * CHUNK + sub * ILG + il;
                const float* xi = xb + i * D_;
                const float2* wp = W2 + (i * C_ + c) * (D_ * O_ / 2) + o2;
                float h0 = 0.0f, h1 = 0.0f;
                #pragma unroll
                for (int d = 0; d < D_; ++d) {
                    float2 w = wp[d * (O_ / 2)];
                    float xv = xi[d];
                    h0 = fmaf(xv, w.x, h0);
                    h1 = fmaf(xv, w.y, h1);
                }
                acc0 += h0; acc1 += h1;
            }
        }
        spart[il][c * O_ + o0]     = acc0;
        spart[il][c * O_ + o0 + 1] = acc1;
    }
    __syncthreads();
    if (tid < C_ * O_) {
        float s = 0.0f;
        #pragma unroll
        for (int k = 0; k < ILG; ++k) s += spart[k][tid];
        sv[tid] = s * (1.0f / C_);
    }
    __syncthreads();
    if (tid < C_) {
        float n2 = 0.0f;
        #pragma unroll
        for (int o = 0; o < O_; ++o) { float t = sv[tid * O_ + o]; n2 = fmaf(t, t, n2); }
        scale[tid] = n2 / ((1.0f + n2) * sqrtf(n2 + EPS_));
    }
    __syncthreads();
    if (tid < C_ * O_) vv[tid] = sv[tid] * scale[tid / O_];
    __syncthreads();
    for (int pass = 1; pass < 3; ++pass) {
        float sa0 = 0.0f, sa1 = 0.0f;
        for (int it = 0; it < NITER; ++it) {
            float h0s[SUBI], h1s[SUBI];
            const float v0 = vv[c * O_ + o0];
            const float v1 = vv[c * O_ + o0 + 1];
            #pragma unroll
            for (int sub = 0; sub < SUBI; ++sub) {
                const int i = it * CHUNK + sub * ILG + il;
                const float* xi = xb + i * D_;
                const float2* wp = W2 + (i * C_ + c) * (D_ * O_ / 2) + o2;
                float h0 = 0.0f, h1 = 0.0f;
                #pragma unroll
                for (int d = 0; d < D_; ++d) {
                    float2 w = wp[d * (O_ / 2)];
                    float xv = xi[d];
                    h0 = fmaf(xv, w.x, h0);
                    h1 = fmaf(xv, w.y, h1);
                }
                h0s[sub] = h0; h1s[sub] = h1;
                float p = h0 * v0 + h1 * v1;
                p += __shfl_xor(p, 1);
                p += __shfl_xor(p, 2);
                p += __shfl_xor(p, 4);
                if (o2 == 0) bias[i * C_ + c] += p;
            }
            __syncthreads();
            if (tid < CHUNK * C_) {
                const int il2 = tid / C_, cc = tid % C_;
                const int i = it * CHUNK + il2;
                float m = -1e30f;
                #pragma unroll
                for (int k = 0; k < C_; ++k) m = fmaxf(m, bias[i * C_ + k]);
                ech[il2][cc] = __expf(bias[i * C_ + cc] - m);
            }
            __syncthreads();
            #pragma unroll
            for (int sub = 0; sub < SUBI; ++sub) {
                const int icx = sub * ILG + il;
                float sum = 0.0f;
                #pragma unroll
                for (int k = 0; k < C_; ++k) sum += ech[icx][k];
                const float route = ech[icx][c] / sum;
                sa0 = fmaf(route, h0s[sub], sa0);
                sa1 = fmaf(route, h1s[sub], sa1);
            }
            __syncthreads();
        }
        spart[il][c * O_ + o0]     = sa0;
        spart[il][c * O_ + o0 + 1] = sa1;
        __syncthreads();
        if (tid < C_ * O_) {
            float s = 0.0f;
            #pragma unroll
            for (int k = 0; k < ILG; ++k) s += spart[k][tid];
            sv[tid] = s;
        }
        __syncthreads();
        if (tid < C_) {
            float n2 = 0.0f;
            #pragma unroll
            for (int o = 0; o < O_; ++o) { float t = sv[tid * O_ + o]; n2 = fmaf(t, t, n2); }
            scale[tid] = n2 / ((1.0f + n2) * sqrtf(n2 + EPS_));
        }
        __syncthreads();
        if (tid < C_ * O_) vv[tid] = sv[tid] * scale[tid / O_];
        __syncthreads();
    }
    if (tid < C_ * O_) out[(size_t)b * C_ * O_ + tid] = vv[tid];
}

// ---------------------------------------------------------------------------
extern "C" void kernel_launch(void* const* d_in, const int* in_sizes, int n_in,
                              void* d_out, int out_size, void* d_ws, size_t ws_size,
                              hipStream_t stream) {
    (void)in_sizes; (void)n_in; (void)out_size;
    const float* x = (const float*)d_in[0];
    const float* W = (const float*)d_in[1];
    float* out = (float*)d_out;

    const size_t hat_b  = (size_t)B_ * I_ * CO_ * sizeof(__hip_bfloat16); // 94.4 MB
    const size_t sp1_b  = (size_t)NIC1 * B_ * CO_ * sizeof(float);        // 11.8 MB
    const size_t need   = hat_b + sp1_b;                                  // ~106 MB

    if (ws_size >= need) {
        char* p = (char*)d_ws;
        __hip_bfloat16* hat = (__hip_bfloat16*)p;  p += hat_b;
        float* sPart1 = (float*)p;

        k1_hat<<<dim3(NIC1, NBT), T1, 0, stream>>>(x, W, hat, sPart1);
        k_route_all<<<B_, TRA, 0, stream>>>(hat, sPart1, out);
    } else {
        capsule_routing_kernel<<<B_, THREADS, 0, stream>>>(x, W, out);
    }
}